// Round 1
// baseline (7710.648 us; speedup 1.0000x reference)
//
#include <hip/hip_runtime.h>
#include <math.h>

constexpr int SEQ   = 2048;
constexpr int DIM   = 1024;
constexpr int NHQ   = 16;
constexpr int NKV   = 4;
constexpr int DH    = 64;
constexpr int GRP   = NHQ / NKV;   // 4
constexpr int FFN   = 4096;
constexpr int VOCAB = 32000;
constexpr int LAY   = 4;
constexpr float REPS = 1e-6f;

// ---------------- RoPE tables (fp64 trig for accuracy at s up to 2047) ------
__global__ void k_rope_table(float* __restrict__ ct, float* __restrict__ st) {
    int idx = blockIdx.x * 256 + threadIdx.x;      // SEQ*32 = 65536 total
    int s = idx >> 5, j = idx & 31;
    double invf = exp(-2.0 * (double)j / (double)DH * log(10000.0));
    double ang  = (double)s * invf;
    ct[idx] = (float)cos(ang);
    st[idx] = (float)sin(ang);
}

// ---------------- embedding gather ----------------
__global__ void k_embed(const float* __restrict__ emb, const int* __restrict__ ids,
                        float* __restrict__ h) {
    int s = blockIdx.x, t = threadIdx.x;           // 256 threads, DIM/4=256 float4
    const float4* src = (const float4*)(emb + (size_t)ids[s] * DIM);
    float4*       dst = (float4*)(h + (size_t)s * DIM);
    dst[t] = src[t];
}

// ---------------- RMSNorm (one block per row) ----------------
__global__ void k_rmsnorm(const float* __restrict__ h, const float* __restrict__ w,
                          float* __restrict__ x) {
    int s = blockIdx.x, t = threadIdx.x;
    float4 v = ((const float4*)(h + (size_t)s * DIM))[t];
    float ss = v.x*v.x + v.y*v.y + v.z*v.z + v.w*v.w;
    #pragma unroll
    for (int off = 32; off; off >>= 1) ss += __shfl_down(ss, off, 64);
    __shared__ float red[4];
    int wid = t >> 6, lane = t & 63;
    if (lane == 0) red[wid] = ss;
    __syncthreads();
    float tot = red[0] + red[1] + red[2] + red[3];
    float rs = rsqrtf(tot / (float)DIM + REPS);
    float4 wf = ((const float4*)w)[t];
    float4 o;
    o.x = wf.x * v.x * rs; o.y = wf.y * v.y * rs;
    o.z = wf.z * v.z * rs; o.w = wf.w * v.w * rs;
    ((float4*)(x + (size_t)s * DIM))[t] = o;
}

// ---------------- RoPE apply (in-place on q and k) ----------------
__global__ void k_rope(float* __restrict__ q, float* __restrict__ k,
                       const float* __restrict__ ct, const float* __restrict__ st) {
    int s = blockIdx.x, t = threadIdx.x;
    // q: NHQ heads * 32 pairs = 512
    for (int p = t; p < NHQ * 32; p += 256) {
        int hh = p >> 5, j = p & 31;
        float c = ct[s*32 + j], sn = st[s*32 + j];
        float* b = q + (size_t)s * (NHQ*DH) + hh*DH;
        float x1 = b[j], x2 = b[j + 32];
        b[j]      = x1 * c - x2 * sn;
        b[j + 32] = x2 * c + x1 * sn;
    }
    // k: NKV heads * 32 pairs = 128
    for (int p = t; p < NKV * 32; p += 256) {
        int hh = p >> 5, j = p & 31;
        float c = ct[s*32 + j], sn = st[s*32 + j];
        float* b = k + (size_t)s * (NKV*DH) + hh*DH;
        float x1 = b[j], x2 = b[j + 32];
        b[j]      = x1 * c - x2 * sn;
        b[j + 32] = x2 * c + x1 * sn;
    }
}

// ---------------- tiled fp32 GEMM: C[M,N] = A[M,K] @ B[K,N] (+bias)(+C) -----
// 64x64 tile, BK=16, 256 threads, 4x4 microkernel. All dims divisible (M%64,
// N%64, K%16 hold for every call site).
template<int ADD_BIAS, int RESIDUAL>
__global__ __launch_bounds__(256) void k_gemm(
        const float* __restrict__ A, const float* __restrict__ B,
        const float* __restrict__ bias, float* __restrict__ C,
        int M, int N, int K) {
    __shared__ float As[16][68];   // A transposed: As[k][m], pad->16B-aligned rows
    __shared__ float Bs[16][64];   // Bs[k][n]
    int t  = threadIdx.x;
    int tx = t & 15, ty = t >> 4;
    int bn = blockIdx.x * 64, bm = blockIdx.y * 64;

    const float* Aptr = A + (size_t)(bm + (t >> 2)) * K + ((t & 3) << 2);
    const float* Bptr = B + (size_t)(t >> 4) * N + bn + ((t & 15) << 2);

    float acc[4][4] = {};
    for (int k0 = 0; k0 < K; k0 += 16) {
        float4 av = *(const float4*)(Aptr + k0);
        float4 bv = *(const float4*)(Bptr + (size_t)k0 * N);
        __syncthreads();
        int ak = (t & 3) << 2, am = t >> 2;
        As[ak+0][am] = av.x; As[ak+1][am] = av.y;
        As[ak+2][am] = av.z; As[ak+3][am] = av.w;
        *(float4*)&Bs[t >> 4][(t & 15) << 2] = bv;
        __syncthreads();
        #pragma unroll
        for (int kk = 0; kk < 16; kk++) {
            float a[4], b[4];
            *(float4*)a = *(const float4*)&As[kk][ty << 2];
            *(float4*)b = *(const float4*)&Bs[kk][tx << 2];
            #pragma unroll
            for (int i = 0; i < 4; i++)
                #pragma unroll
                for (int j = 0; j < 4; j++)
                    acc[i][j] = fmaf(a[i], b[j], acc[i][j]);
        }
    }
    float bvals[4] = {0.f, 0.f, 0.f, 0.f};
    if (ADD_BIAS) *(float4*)bvals = *(const float4*)(bias + bn + (tx << 2));
    #pragma unroll
    for (int i = 0; i < 4; i++) {
        int r = bm + (ty << 2) + i;
        float* crow = C + (size_t)r * N + bn + (tx << 2);
        float4 res;
        res.x = acc[i][0] + bvals[0];
        res.y = acc[i][1] + bvals[1];
        res.z = acc[i][2] + bvals[2];
        res.w = acc[i][3] + bvals[3];
        if (RESIDUAL) {
            float4 old = *(const float4*)crow;
            res.x += old.x; res.y += old.y; res.z += old.z; res.w += old.w;
        }
        *(float4*)crow = res;
    }
}

// ---------------- flash attention, fp32, Br=Bc=64 ----------------
// grid: (SEQ/64, NHQ). LDS: Qs,Ks,Vs [64][68]; P reuses Ks. <64KB total.
__global__ __launch_bounds__(256) void k_attn(
        const float* __restrict__ q, const float* __restrict__ kbuf,
        const float* __restrict__ vbuf, float* __restrict__ o) {
    __shared__ float Qs[64][68];   // Qs[d][r]  (transposed, pre-scaled)
    __shared__ float Ks[64][68];   // Ks[d][c]  (transposed); reused as Ps[c][r]
    __shared__ float Vs[64][68];   // Vs[c][d]
    __shared__ float red[64][17];
    __shared__ float row_m[64], row_l[64], row_al[64];
    float (*Ps)[68] = Ks;

    int t  = threadIdx.x;
    int tx = t & 15, ty = t >> 4;
    int qt = blockIdx.x, hh = blockIdx.y;
    int kvh = hh >> 2;                       // hh / GRP
    const float scale = 0.125f;              // 1/sqrt(64)

    // stage Q (scaled)
    #pragma unroll
    for (int m = 0; m < 4; m++) {
        int idx = t + 256 * m;
        int r = idx >> 4, c4 = (idx & 15) << 2;
        float4 qv = *(const float4*)(q + (size_t)(qt*64 + r) * (NHQ*DH) + hh*DH + c4);
        Qs[c4+0][r] = qv.x * scale; Qs[c4+1][r] = qv.y * scale;
        Qs[c4+2][r] = qv.z * scale; Qs[c4+3][r] = qv.w * scale;
    }
    if (t < 64) { row_m[t] = -INFINITY; row_l[t] = 0.f; }

    float oacc[4][4] = {};
    for (int kt = 0; kt <= qt; kt++) {
        __syncthreads();   // prev-iter PV reads & (kt==0) Q staging done
        // stage K (transposed) and V
        #pragma unroll
        for (int m = 0; m < 4; m++) {
            int idx = t + 256 * m;
            int r = idx >> 4, c4 = (idx & 15) << 2;
            const float* kp = kbuf + (size_t)(kt*64 + r) * (NKV*DH) + kvh*DH + c4;
            float4 kv = *(const float4*)kp;
            Ks[c4+0][r] = kv.x; Ks[c4+1][r] = kv.y;
            Ks[c4+2][r] = kv.z; Ks[c4+3][r] = kv.w;
            const float* vp = vbuf + (size_t)(kt*64 + r) * (NKV*DH) + kvh*DH + c4;
            *(float4*)&Vs[r][c4] = *(const float4*)vp;
        }
        __syncthreads();
        // S = (Q*scale) K^T
        float sacc[4][4] = {};
        #pragma unroll
        for (int d = 0; d < 64; d++) {
            float a[4], b[4];
            *(float4*)a = *(const float4*)&Qs[d][ty << 2];
            *(float4*)b = *(const float4*)&Ks[d][tx << 2];
            #pragma unroll
            for (int i = 0; i < 4; i++)
                #pragma unroll
                for (int j = 0; j < 4; j++)
                    sacc[i][j] = fmaf(a[i], b[j], sacc[i][j]);
        }
        if (kt == qt) {    // diagonal tile: mask j > i
            #pragma unroll
            for (int i = 0; i < 4; i++)
                #pragma unroll
                for (int j = 0; j < 4; j++)
                    if ((tx << 2) + j > (ty << 2) + i) sacc[i][j] = -1e30f;
        }
        // row max partials
        #pragma unroll
        for (int i = 0; i < 4; i++) {
            float mx = fmaxf(fmaxf(sacc[i][0], sacc[i][1]), fmaxf(sacc[i][2], sacc[i][3]));
            red[(ty << 2) + i][tx] = mx;
        }
        __syncthreads();
        if (t < 64) {
            float mt = red[t][0];
            #pragma unroll
            for (int u2 = 1; u2 < 16; u2++) mt = fmaxf(mt, red[t][u2]);
            float mo = row_m[t];
            float mn = fmaxf(mo, mt);
            row_al[t] = __expf(mo - mn);
            row_m[t]  = mn;
        }
        __syncthreads();
        // p = exp(s - m_new) -> Ps (transposed), row-sum partials
        #pragma unroll
        for (int i = 0; i < 4; i++) {
            float mn = row_m[(ty << 2) + i];
            float psum = 0.f;
            #pragma unroll
            for (int j = 0; j < 4; j++) {
                float p = __expf(sacc[i][j] - mn);
                Ps[(tx << 2) + j][(ty << 2) + i] = p;
                psum += p;
            }
            red[(ty << 2) + i][tx] = psum;
        }
        __syncthreads();
        if (t < 64) {
            float ssum = 0.f;
            #pragma unroll
            for (int u2 = 0; u2 < 16; u2++) ssum += red[t][u2];
            row_l[t] = row_al[t] * row_l[t] + ssum;
        }
        // rescale O, then O += P V
        float al[4];
        #pragma unroll
        for (int i = 0; i < 4; i++) al[i] = row_al[(ty << 2) + i];
        #pragma unroll
        for (int i = 0; i < 4; i++)
            #pragma unroll
            for (int j = 0; j < 4; j++) oacc[i][j] *= al[i];
        #pragma unroll
        for (int c = 0; c < 64; c++) {
            float a[4], b[4];
            *(float4*)a = *(const float4*)&Ps[c][ty << 2];
            *(float4*)b = *(const float4*)&Vs[c][tx << 2];
            #pragma unroll
            for (int i = 0; i < 4; i++)
                #pragma unroll
                for (int j = 0; j < 4; j++)
                    oacc[i][j] = fmaf(a[i], b[j], oacc[i][j]);
        }
    }
    __syncthreads();
    #pragma unroll
    for (int i = 0; i < 4; i++) {
        int r = (ty << 2) + i;
        float inv = 1.0f / row_l[r];
        float4 ov;
        ov.x = oacc[i][0] * inv; ov.y = oacc[i][1] * inv;
        ov.z = oacc[i][2] * inv; ov.w = oacc[i][3] * inv;
        *(float4*)(o + (size_t)(qt*64 + r) * (NHQ*DH) + hh*DH + (tx << 2)) = ov;
    }
}

// ---------------- silu(g) * u, in-place into g ----------------
__global__ void k_silu_mul(float* __restrict__ g, const float* __restrict__ u, int n4) {
    int i = blockIdx.x * 256 + threadIdx.x;
    if (i >= n4) return;
    float4 gv = ((const float4*)g)[i];
    float4 uv = ((const float4*)u)[i];
    float4 r;
    r.x = gv.x / (1.f + __expf(-gv.x)) * uv.x;
    r.y = gv.y / (1.f + __expf(-gv.y)) * uv.y;
    r.z = gv.z / (1.f + __expf(-gv.z)) * uv.z;
    r.w = gv.w / (1.f + __expf(-gv.w)) * uv.w;
    ((float4*)g)[i] = r;
}

extern "C" void kernel_launch(void* const* d_in, const int* in_sizes, int n_in,
                              void* d_out, int out_size, void* d_ws, size_t ws_size,
                              hipStream_t stream) {
    const float* emb    = (const float*)d_in[0];
    const float* ln1    = (const float*)d_in[1];
    const float* qw     = (const float*)d_in[2];
    const float* qbias  = (const float*)d_in[3];
    const float* kw     = (const float*)d_in[4];
    const float* kbias  = (const float*)d_in[5];
    const float* vw     = (const float*)d_in[6];
    const float* vbias  = (const float*)d_in[7];
    const float* ow     = (const float*)d_in[8];
    const float* ln2    = (const float*)d_in[9];
    const float* gw     = (const float*)d_in[10];
    const float* uw     = (const float*)d_in[11];
    const float* dw     = (const float*)d_in[12];
    const float* norm_w = (const float*)d_in[13];
    const float* lm_w   = (const float*)d_in[14];
    const int*   ids    = (const int*)d_in[15];
    float* out = (float*)d_out;

    float* ws   = (float*)d_ws;
    float* h    = ws;
    float* x    = h    + (size_t)SEQ * DIM;
    float* qb_  = x    + (size_t)SEQ * DIM;
    float* kb_  = qb_  + (size_t)SEQ * NHQ * DH;
    float* vb_  = kb_  + (size_t)SEQ * NKV * DH;
    float* ob_  = vb_  + (size_t)SEQ * NKV * DH;
    float* gbuf = ob_  + (size_t)SEQ * NHQ * DH;
    float* ubuf = gbuf + (size_t)SEQ * FFN;
    float* ct   = ubuf + (size_t)SEQ * FFN;
    float* st   = ct   + (size_t)SEQ * 32;

    k_rope_table<<<SEQ * 32 / 256, 256, 0, stream>>>(ct, st);
    k_embed<<<SEQ, 256, 0, stream>>>(emb, ids, h);

    for (int l = 0; l < LAY; l++) {
        const float* qw_l = qw + (size_t)l * DIM * NHQ * DH;
        const float* kw_l = kw + (size_t)l * DIM * NKV * DH;
        const float* vw_l = vw + (size_t)l * DIM * NKV * DH;
        const float* ow_l = ow + (size_t)l * NHQ * DH * DIM;
        const float* gw_l = gw + (size_t)l * DIM * FFN;
        const float* uw_l = uw + (size_t)l * DIM * FFN;
        const float* dw_l = dw + (size_t)l * FFN * DIM;

        k_rmsnorm<<<SEQ, 256, 0, stream>>>(h, ln1 + (size_t)l * DIM, x);
        k_gemm<1,0><<<dim3(NHQ*DH/64, SEQ/64), 256, 0, stream>>>(
            x, qw_l, qbias + (size_t)l * NHQ * DH, qb_, SEQ, NHQ*DH, DIM);
        k_gemm<1,0><<<dim3(NKV*DH/64, SEQ/64), 256, 0, stream>>>(
            x, kw_l, kbias + (size_t)l * NKV * DH, kb_, SEQ, NKV*DH, DIM);
        k_gemm<1,0><<<dim3(NKV*DH/64, SEQ/64), 256, 0, stream>>>(
            x, vw_l, vbias + (size_t)l * NKV * DH, vb_, SEQ, NKV*DH, DIM);
        k_rope<<<SEQ, 256, 0, stream>>>(qb_, kb_, ct, st);
        k_attn<<<dim3(SEQ/64, NHQ), 256, 0, stream>>>(qb_, kb_, vb_, ob_);
        k_gemm<0,1><<<dim3(DIM/64, SEQ/64), 256, 0, stream>>>(
            ob_, ow_l, nullptr, h, SEQ, DIM, NHQ*DH);
        k_rmsnorm<<<SEQ, 256, 0, stream>>>(h, ln2 + (size_t)l * DIM, x);
        k_gemm<0,0><<<dim3(FFN/64, SEQ/64), 256, 0, stream>>>(
            x, gw_l, nullptr, gbuf, SEQ, FFN, DIM);
        k_gemm<0,0><<<dim3(FFN/64, SEQ/64), 256, 0, stream>>>(
            x, uw_l, nullptr, ubuf, SEQ, FFN, DIM);
        k_silu_mul<<<(SEQ * FFN / 4 + 255) / 256, 256, 0, stream>>>(
            gbuf, ubuf, SEQ * FFN / 4);
        k_gemm<0,1><<<dim3(DIM/64, SEQ/64), 256, 0, stream>>>(
            gbuf, dw_l, nullptr, h, SEQ, DIM, FFN);
    }
    k_rmsnorm<<<SEQ, 256, 0, stream>>>(h, norm_w, x);
    k_gemm<0,0><<<dim3(VOCAB/64, SEQ/64), 256, 0, stream>>>(
        x, lm_w, nullptr, out, SEQ, VOCAB, DIM);
}